// Round 1
// baseline (440.416 us; speedup 1.0000x reference)
//
#include <hip/hip_runtime.h>

#define FEAT_H 32
#define FEAT_W 110
#define STRIDEPX 16
#define NB 8
#define NG 32
#define NANC 36
#define NC 4
#define A_TOTAL (FEAT_H * FEAT_W * NANC) /* 126720 */
#define BLK 256
#define CHUNKS (A_TOTAL / BLK) /* 495, exact */

__device__ __forceinline__ float smooth_l1(float x) {
    float ax = fabsf(x);
    return ax < 1.f ? 0.5f * ax * ax : ax - 0.5f;
}

__global__ void k_init(float* acc) {
    if (threadIdx.x < 8) acc[threadIdx.x] = 0.f;
}

// One block per (b,g): exact first-occurrence argmax over all anchors via
// packed (iou_bits<<32)|(0xFFFFFFFF - a) max-reduction. IoU >= 0 so float
// bits are monotone as uint.
__global__ __launch_bounds__(BLK) void k_col(const float* __restrict__ gt_boxes,
                                             const int* __restrict__ gt_valid,
                                             const float* __restrict__ anchors,
                                             int* __restrict__ ba_out,
                                             int* __restrict__ force_out) {
#pragma clang fp contract(off)
    __shared__ float anch[NANC * 4];
    __shared__ unsigned long long wbest[BLK / 64];
    const int tid = threadIdx.x;
    const int b = blockIdx.x / NG, g = blockIdx.x % NG;
    for (int i = tid; i < NANC * 4; i += BLK) anch[i] = anchors[(i >> 2) * 9 + (i & 3)];
    __syncthreads();
    if (!gt_valid[b * NG + g]) {
        if (tid == 0) { ba_out[b * NG + g] = 0; force_out[b * NG + g] = 0; }
        return;
    }
    const float g0 = gt_boxes[(b * NG + g) * 4 + 0];
    const float g1 = gt_boxes[(b * NG + g) * 4 + 1];
    const float g2 = gt_boxes[(b * NG + g) * 4 + 2];
    const float g3 = gt_boxes[(b * NG + g) * 4 + 3];
    const float ag = (g2 - g0 + 1.f) * (g3 - g1 + 1.f);
    unsigned long long best = 0ull;
    for (int a = tid; a < A_TOTAL; a += BLK) {
        const int t = a % NANC;
        const int cell = a / NANC;
        const float sx = (float)((cell % FEAT_W) * STRIDEPX);
        const float sy = (float)((cell / FEAT_W) * STRIDEPX);
        const float r0 = sx + anch[t * 4 + 0], r1 = sy + anch[t * 4 + 1];
        const float r2 = sx + anch[t * 4 + 2], r3 = sy + anch[t * 4 + 3];
        const float xx1 = fmaxf(r0, g0), yy1 = fmaxf(r1, g1);
        const float xx2 = fminf(r2, g2), yy2 = fminf(r3, g3);
        const float iw = fmaxf(xx2 - xx1 + 1.f, 0.f);
        const float ih = fmaxf(yy2 - yy1 + 1.f, 0.f);
        const float inter = iw * ih;
        const float ar = (r2 - r0 + 1.f) * (r3 - r1 + 1.f);
        const float iou = inter / (ar + ag - inter);
        unsigned long long p = ((unsigned long long)__float_as_uint(iou) << 32) |
                               (unsigned long long)(0xFFFFFFFFu - (unsigned)a);
        if (p > best) best = p;
    }
    for (int off = 32; off; off >>= 1) {
        unsigned long long o = __shfl_down(best, off, 64);
        if (o > best) best = o;
    }
    if ((tid & 63) == 0) wbest[tid >> 6] = best;
    __syncthreads();
    if (tid == 0) {
        for (int w = 1; w < BLK / 64; ++w)
            if (wbest[w] > best) best = wbest[w];
        const float gt_best = __uint_as_float((unsigned)(best >> 32));
        ba_out[b * NG + g] = (int)(0xFFFFFFFFu - (unsigned)(best & 0xFFFFFFFFull));
        force_out[b * NG + g] = (gt_best >= 0.35f) ? 1 : 0;
    }
}

// One thread per (b,a). acc layout: [0]=sum_ce, [1]=n_act, [2]=n_fg,
// [3]=sum_2d, [4]=sum_3d.
__global__ __launch_bounds__(BLK) void k_main(
    const float* __restrict__ cls, const float* __restrict__ bbox_2d,
    const float* __restrict__ bbox_3d, const float* __restrict__ gt_boxes,
    const float* __restrict__ gt_3d, const int* __restrict__ gt_labels,
    const int* __restrict__ gt_valid, const float* __restrict__ anchors,
    const float* __restrict__ means, const float* __restrict__ stds,
    const int* __restrict__ ba, const int* __restrict__ force,
    float* __restrict__ acc) {
#pragma clang fp contract(off)
    __shared__ float anch[NANC * 9];
    __shared__ float gtb_s[NG * 4];
    __shared__ float gt3_s[NG * 7];
    __shared__ int lbl_s[NG], val_s[NG], ba_s[NG], force_s[NG];
    __shared__ float mean_s[11], std_s[11];
    __shared__ float red[5][BLK / 64];
    const int tid = threadIdx.x;
    const int b = blockIdx.x / CHUNKS;
    const int chunk = blockIdx.x % CHUNKS;
    for (int i = tid; i < NANC * 9; i += BLK) anch[i] = anchors[i];
    for (int i = tid; i < NG * 4; i += BLK) gtb_s[i] = gt_boxes[b * NG * 4 + i];
    for (int i = tid; i < NG * 7; i += BLK) gt3_s[i] = gt_3d[b * NG * 7 + i];
    if (tid < NG) {
        lbl_s[tid] = gt_labels[b * NG + tid];
        val_s[tid] = gt_valid[b * NG + tid];
        ba_s[tid] = ba[b * NG + tid];
        force_s[tid] = force[b * NG + tid];
    }
    if (tid < 11) { mean_s[tid] = means[tid]; std_s[tid] = stds[tid]; }
    __syncthreads();

    const int a = chunk * BLK + tid;
    const int t = a % NANC;
    const int cell = a / NANC;
    const float sx = (float)((cell % FEAT_W) * STRIDEPX);
    const float sy = (float)((cell / FEAT_W) * STRIDEPX);
    const float r0 = sx + anch[t * 9 + 0], r1 = sy + anch[t * 9 + 1];
    const float r2 = sx + anch[t * 9 + 2], r3 = sy + anch[t * 9 + 3];
    const float ar = (r2 - r0 + 1.f) * (r3 - r1 + 1.f);

    // per-anchor row max / first-occurrence argmax over masked IoU
    float best = -1.0f;
    int agt = 0;
    for (int g = 0; g < NG; ++g) {
        const float q0 = gtb_s[g * 4 + 0], q1 = gtb_s[g * 4 + 1];
        const float q2 = gtb_s[g * 4 + 2], q3 = gtb_s[g * 4 + 3];
        const float xx1 = fmaxf(r0, q0), yy1 = fmaxf(r1, q1);
        const float xx2 = fminf(r2, q2), yy2 = fminf(r3, q3);
        const float iw = fmaxf(xx2 - xx1 + 1.f, 0.f);
        const float ih = fmaxf(yy2 - yy1 + 1.f, 0.f);
        const float inter = iw * ih;
        const float aq = (q2 - q0 + 1.f) * (q3 - q1 + 1.f);
        float iou = inter / (ar + aq - inter);
        if (!val_s[g]) iou = -1.0f;
        if (iou > best) { best = iou; agt = g; }
    }
    bool fg = best >= 0.5f;
    const int agt_orig = agt;
    // Emulate fg.at[ba].max(force) and agt.at[ba].set(where(force, g, agt[ba]))
    // with gather-before-scatter + last-update-wins semantics.
    for (int g = 0; g < NG; ++g) {
        if (a == ba_s[g]) {
            if (force_s[g]) { agt = g; fg = true; }
            else            { agt = agt_orig; }
        }
    }
    const bool bg = (!fg) && (best < 0.5f) && (best >= 0.0f);
    const float active = (fg || bg) ? 1.f : 0.f;
    const int lbl = fg ? lbl_s[agt] : 0;

    // cross-entropy via log-softmax
    const float* c = cls + ((size_t)(b * A_TOTAL + a)) * NC;
    const float c0 = c[0], c1 = c[1], c2 = c[2], c3 = c[3];
    const float m = fmaxf(fmaxf(c0, c1), fmaxf(c2, c3));
    const float lse = m + logf(expf(c0 - m) + expf(c1 - m) + expf(c2 - m) + expf(c3 - m));
    const float csel = (lbl == 0) ? c0 : (lbl == 1) ? c1 : (lbl == 2) ? c2 : c3;
    const float ce = (lse - csel) * active;

    float l2 = 0.f, l3 = 0.f;
    const float fgf = fg ? 1.f : 0.f;
    if (fg) {
        const float w = r2 - r0 + 1.f, h = r3 - r1 + 1.f;
        const float cx = r0 + 0.5f * w, cy = r1 + 0.5f * h;
        const float G0 = gtb_s[agt * 4 + 0], G1 = gtb_s[agt * 4 + 1];
        const float G2 = gtb_s[agt * 4 + 2], G3 = gtb_s[agt * 4 + 3];
        const float gw = G2 - G0 + 1.f, gh = G3 - G1 + 1.f;
        const float gcx = G0 + 0.5f * gw, gcy = G1 + 0.5f * gh;
        float t2[4];
        t2[0] = (gcx - cx) / w;
        t2[1] = (gcy - cy) / h;
        t2[2] = logf(gw / w);
        t2[3] = logf(gh / h);
        const float* b2 = bbox_2d + ((size_t)(b * A_TOTAL + a)) * 4;
        for (int k = 0; k < 4; ++k) {
            const float tv = (t2[k] - mean_s[k]) / std_s[k];
            l2 += smooth_l1(b2[k] - tv);
        }
        const float* q3p = &gt3_s[agt * 7];
        const float s4 = anch[t * 9 + 4], s5 = anch[t * 9 + 5];
        const float s6 = anch[t * 9 + 6], s7 = anch[t * 9 + 7], s8 = anch[t * 9 + 8];
        float t3[7];
        t3[0] = (q3p[0] - cx) / w;
        t3[1] = (q3p[1] - cy) / h;
        t3[2] = q3p[2] - s4;
        t3[3] = logf(q3p[3] / s5);
        t3[4] = logf(q3p[4] / s6);
        t3[5] = logf(q3p[5] / s7);
        t3[6] = q3p[6] - s8;
        const float* b3 = bbox_3d + ((size_t)(b * A_TOTAL + a)) * 7;
        for (int k = 0; k < 7; ++k) {
            const float tv = (t3[k] - mean_s[4 + k]) / std_s[4 + k];
            l3 += smooth_l1(b3[k] - tv);
        }
    }

    // block reduce 5 partials -> one atomicAdd set per block
    float vals[5] = {ce, active, fgf, l2 * fgf, l3 * fgf};
    for (int j = 0; j < 5; ++j) {
        float v = vals[j];
        for (int off = 32; off; off >>= 1) v += __shfl_down(v, off, 64);
        if ((tid & 63) == 0) red[j][tid >> 6] = v;
        vals[j] = v;
    }
    __syncthreads();
    if (tid == 0) {
        for (int j = 0; j < 5; ++j) {
            float s = 0.f;
            for (int w = 0; w < BLK / 64; ++w) s += red[j][w];
            atomicAdd(&acc[j], s);
        }
    }
}

__global__ void k_fin(const float* __restrict__ acc, float* __restrict__ out) {
    if (threadIdx.x == 0 && blockIdx.x == 0) {
        const float nact = fmaxf(acc[1], 1.f);
        const float nfg = fmaxf(acc[2], 1.f);
        out[0] = acc[0] / nact + acc[3] / nfg + acc[4] / nfg;
    }
}

extern "C" void kernel_launch(void* const* d_in, const int* in_sizes, int n_in,
                              void* d_out, int out_size, void* d_ws, size_t ws_size,
                              hipStream_t stream) {
    const float* cls      = (const float*)d_in[0];
    const float* bbox_2d  = (const float*)d_in[1];
    const float* bbox_3d  = (const float*)d_in[2];
    const float* gt_boxes = (const float*)d_in[3];
    const float* gt_3d    = (const float*)d_in[4];
    const int*   gt_labels= (const int*)d_in[5];
    const int*   gt_valid = (const int*)d_in[6];
    const float* anchors  = (const float*)d_in[7];
    const float* means    = (const float*)d_in[8];
    const float* stds     = (const float*)d_in[9];

    float* acc   = (float*)d_ws;                                    // 8 floats
    int*   ba    = (int*)((char*)d_ws + 64);                        // NB*NG ints
    int*   force = (int*)((char*)d_ws + 64 + NB * NG * sizeof(int));// NB*NG ints
    float* out   = (float*)d_out;

    k_init<<<1, 64, 0, stream>>>(acc);
    k_col<<<NB * NG, BLK, 0, stream>>>(gt_boxes, gt_valid, anchors, ba, force);
    k_main<<<NB * CHUNKS, BLK, 0, stream>>>(cls, bbox_2d, bbox_3d, gt_boxes, gt_3d,
                                            gt_labels, gt_valid, anchors, means,
                                            stds, ba, force, acc);
    k_fin<<<1, 64, 0, stream>>>(acc, out);
}

// Round 2
// 396.689 us; speedup vs baseline: 1.1102x; 1.1102x over previous
//
#include <hip/hip_runtime.h>

#define FEAT_H 32
#define FEAT_W 110
#define STRIDEPX 16
#define NB 8
#define NG 32
#define NANC 36
#define NC 4
#define A_TOTAL (FEAT_H * FEAT_W * NANC) /* 126720 */
#define BLK 256
#define CHUNKS (A_TOTAL / BLK) /* 495, exact */
#define COLCH 16               /* chunks per (b,g) column */

__device__ __forceinline__ float smooth_l1(float x) {
    float ax = fabsf(x);
    return ax < 1.f ? 0.5f * ax * ax : ax - 0.5f;
}

// ws: acc[8] floats @0, colmax[NB*NG] u64 @64
__global__ void k_init(float* acc, unsigned long long* colmax) {
    const int tid = threadIdx.x;
    if (tid < 8) acc[tid] = 0.f;
    if (tid < NB * NG) colmax[tid] = 0ull;
}

// Column argmax: one block per (b,g,chunk). Packed (iou_bits<<32)|(~a) max
// gives exact first-occurrence argmax (smallest a among ties). IoU >= 0 so
// float bits are monotone as uint. Invalid (b,g) columns are skipped ->
// colmax stays 0; k_main decodes that as ba=0, force=0 (reference semantics).
__global__ __launch_bounds__(BLK) void k_colpass(
    const float* __restrict__ gt_boxes, const int* __restrict__ gt_valid,
    const float* __restrict__ anchors, unsigned long long* __restrict__ colmax) {
#pragma clang fp contract(off)
    __shared__ float4 anch4[NANC];
    __shared__ unsigned long long wbest[BLK / 64];
    const int tid = threadIdx.x;
    const int chunk = blockIdx.x % COLCH;
    const int bg = blockIdx.x / COLCH;
    if (!gt_valid[bg]) return; // block-uniform exit, before any barrier
    if (tid < NANC) {
        const float* ap = anchors + tid * 9;
        anch4[tid] = make_float4(ap[0], ap[1], ap[2], ap[3]);
    }
    __syncthreads();
    // wave-uniform GT box -> scalar loads
    const float g0 = gt_boxes[bg * 4 + 0], g1 = gt_boxes[bg * 4 + 1];
    const float g2 = gt_boxes[bg * 4 + 2], g3 = gt_boxes[bg * 4 + 3];
    const float ag = (g2 - g0 + 1.f) * (g3 - g1 + 1.f);
    unsigned long long best = 0ull;
    for (int a = chunk * BLK + tid; a < A_TOTAL; a += COLCH * BLK) {
        const int t = a % NANC;
        const int cell = a / NANC;
        const float sx = (float)((cell % FEAT_W) * STRIDEPX);
        const float sy = (float)((cell / FEAT_W) * STRIDEPX);
        const float4 av = anch4[t];
        const float r0 = sx + av.x, r1 = sy + av.y;
        const float r2 = sx + av.z, r3 = sy + av.w;
        const float xx1 = fmaxf(r0, g0), yy1 = fmaxf(r1, g1);
        const float xx2 = fminf(r2, g2), yy2 = fminf(r3, g3);
        const float iw = fmaxf(xx2 - xx1 + 1.f, 0.f);
        const float ih = fmaxf(yy2 - yy1 + 1.f, 0.f);
        const float inter = iw * ih;
        const float ar = (r2 - r0 + 1.f) * (r3 - r1 + 1.f);
        const float iou = inter * __builtin_amdgcn_rcpf(ar + ag - inter);
        unsigned long long p = ((unsigned long long)__float_as_uint(iou) << 32) |
                               (unsigned long long)(0xFFFFFFFFu - (unsigned)a);
        if (p > best) best = p;
    }
    for (int off = 32; off; off >>= 1) {
        unsigned long long o = __shfl_down(best, off, 64);
        if (o > best) best = o;
    }
    if ((tid & 63) == 0) wbest[tid >> 6] = best;
    __syncthreads();
    if (tid == 0) {
        for (int w = 1; w < BLK / 64; ++w)
            if (wbest[w] > best) best = wbest[w];
        atomicMax(&colmax[bg], best);
    }
}

// One thread per (b,a). acc: [0]=sum_ce, [1]=n_act, [2]=n_fg, [3]=sum_2d, [4]=sum_3d.
__global__ __launch_bounds__(BLK) void k_main(
    const float* __restrict__ cls, const float* __restrict__ bbox_2d,
    const float* __restrict__ bbox_3d, const float* __restrict__ gt_boxes,
    const float* __restrict__ gt_3d, const int* __restrict__ gt_labels,
    const int* __restrict__ gt_valid, const float* __restrict__ anchors,
    const float* __restrict__ means, const float* __restrict__ stds,
    const unsigned long long* __restrict__ colmax, float* __restrict__ acc) {
#pragma clang fp contract(off)
    __shared__ float anch[NANC * 9];
    __shared__ float4 gtb4_s[NG];
    __shared__ float ags_s[NG];
    __shared__ float gt3_s[NG * 7];
    __shared__ int lbl_s[NG];
    __shared__ int fix_s[NG]; // ba | (force<<31)
    __shared__ float mean_s[11], std_s[11];
    __shared__ unsigned vmask_s;
    __shared__ float red[5][BLK / 64];
    const int tid = threadIdx.x;
    const int b = blockIdx.x / CHUNKS;
    const int chunk = blockIdx.x % CHUNKS;
    for (int i = tid; i < NANC * 9; i += BLK) anch[i] = anchors[i];
    for (int i = tid; i < NG * 7; i += BLK) gt3_s[i] = gt_3d[b * NG * 7 + i];
    int myval = 0;
    if (tid < NG) {
        const float4 q = ((const float4*)gt_boxes)[b * NG + tid];
        gtb4_s[tid] = q;
        ags_s[tid] = (q.z - q.x + 1.f) * (q.w - q.y + 1.f);
        lbl_s[tid] = gt_labels[b * NG + tid];
        myval = gt_valid[b * NG + tid];
        const unsigned long long p = colmax[b * NG + tid];
        const float gbest = __uint_as_float((unsigned)(p >> 32));
        const int ba = myval ? (int)(0xFFFFFFFFu - (unsigned)(p & 0xFFFFFFFFull)) : 0;
        const int force = (myval && gbest >= 0.35f) ? 1 : 0;
        fix_s[tid] = ba | (force << 31);
    }
    // valid bitmask via wave-0 ballot (lanes 0..31 hold g=0..31)
    unsigned long long bal = __ballot(tid < NG && myval);
    if (tid == 0) vmask_s = (unsigned)bal;
    if (tid < 11) { mean_s[tid] = means[tid]; std_s[tid] = stds[tid]; }
    __syncthreads();

    const int a = chunk * BLK + tid;
    const int t = a % NANC;
    const int cell = a / NANC;
    const float sx = (float)((cell % FEAT_W) * STRIDEPX);
    const float sy = (float)((cell / FEAT_W) * STRIDEPX);
    const float r0 = sx + anch[t * 9 + 0], r1 = sy + anch[t * 9 + 1];
    const float r2 = sx + anch[t * 9 + 2], r3 = sy + anch[t * 9 + 3];
    const float ar = (r2 - r0 + 1.f) * (r3 - r1 + 1.f);
    const unsigned vmask = vmask_s;

    // prefetch cls early to overlap global latency with the IoU loop
    const float4 cv = *(const float4*)(cls + ((size_t)(b * A_TOTAL + a)) * NC);

    // per-anchor row max / first-occurrence argmax over masked IoU
    float best = -1.0f;
    int agt = 0;
#pragma unroll
    for (int g = 0; g < NG; ++g) {
        const float4 q = gtb4_s[g];
        const float xx1 = fmaxf(r0, q.x), yy1 = fmaxf(r1, q.y);
        const float xx2 = fminf(r2, q.z), yy2 = fminf(r3, q.w);
        const float iw = fmaxf(xx2 - xx1 + 1.f, 0.f);
        const float ih = fmaxf(yy2 - yy1 + 1.f, 0.f);
        const float inter = iw * ih;
        float iou = inter * __builtin_amdgcn_rcpf(ar + ags_s[g] - inter);
        iou = ((vmask >> g) & 1u) ? iou : -1.0f;
        if (iou > best) { best = iou; agt = g; }
    }
    bool fg = best >= 0.5f;
    const int agt_orig = agt;
    // fg.at[ba].max(force); agt.at[ba].set(where(force, g, agt_orig[ba]))
    // gather-before-scatter + last-update-wins, duplicates included.
#pragma unroll
    for (int g = 0; g < NG; ++g) {
        const int f = fix_s[g];
        if (a == (f & 0x7FFFFFFF)) {
            if (f < 0) { agt = g; fg = true; }
            else       { agt = agt_orig; }
        }
    }
    const bool bg = (!fg) && (best < 0.5f) && (best >= 0.0f);
    const float active = (fg || bg) ? 1.f : 0.f;
    const int lbl = fg ? lbl_s[agt] : 0;

    // cross-entropy via log-softmax
    const float c0 = cv.x, c1 = cv.y, c2 = cv.z, c3 = cv.w;
    const float m = fmaxf(fmaxf(c0, c1), fmaxf(c2, c3));
    const float lse = m + logf(expf(c0 - m) + expf(c1 - m) + expf(c2 - m) + expf(c3 - m));
    const float csel = (lbl == 0) ? c0 : (lbl == 1) ? c1 : (lbl == 2) ? c2 : c3;
    const float ce = (lse - csel) * active;

    float l2 = 0.f, l3 = 0.f;
    const float fgf = fg ? 1.f : 0.f;
    if (fg) {
        const float w = r2 - r0 + 1.f, h = r3 - r1 + 1.f;
        const float cx = r0 + 0.5f * w, cy = r1 + 0.5f * h;
        const float4 G = gtb4_s[agt];
        const float gw = G.z - G.x + 1.f, gh = G.w - G.y + 1.f;
        const float gcx = G.x + 0.5f * gw, gcy = G.y + 0.5f * gh;
        float t2[4];
        t2[0] = (gcx - cx) / w;
        t2[1] = (gcy - cy) / h;
        t2[2] = logf(gw / w);
        t2[3] = logf(gh / h);
        const float4 b2 = *(const float4*)(bbox_2d + ((size_t)(b * A_TOTAL + a)) * 4);
        const float b2v[4] = {b2.x, b2.y, b2.z, b2.w};
        for (int k = 0; k < 4; ++k) {
            const float tv = (t2[k] - mean_s[k]) / std_s[k];
            l2 += smooth_l1(b2v[k] - tv);
        }
        const float* q3p = &gt3_s[agt * 7];
        const float s4 = anch[t * 9 + 4], s5 = anch[t * 9 + 5];
        const float s6 = anch[t * 9 + 6], s7 = anch[t * 9 + 7], s8 = anch[t * 9 + 8];
        float t3[7];
        t3[0] = (q3p[0] - cx) / w;
        t3[1] = (q3p[1] - cy) / h;
        t3[2] = q3p[2] - s4;
        t3[3] = logf(q3p[3] / s5);
        t3[4] = logf(q3p[4] / s6);
        t3[5] = logf(q3p[5] / s7);
        t3[6] = q3p[6] - s8;
        const float* b3 = bbox_3d + ((size_t)(b * A_TOTAL + a)) * 7;
        for (int k = 0; k < 7; ++k) {
            const float tv = (t3[k] - mean_s[4 + k]) / std_s[4 + k];
            l3 += smooth_l1(b3[k] - tv);
        }
    }

    // block reduce 5 partials -> one atomicAdd set per block
    float vals[5] = {ce, active, fgf, l2 * fgf, l3 * fgf};
#pragma unroll
    for (int j = 0; j < 5; ++j) {
        float v = vals[j];
        for (int off = 32; off; off >>= 1) v += __shfl_down(v, off, 64);
        if ((tid & 63) == 0) red[j][tid >> 6] = v;
    }
    __syncthreads();
    if (tid == 0) {
        for (int j = 0; j < 5; ++j) {
            float s = 0.f;
            for (int w = 0; w < BLK / 64; ++w) s += red[j][w];
            atomicAdd(&acc[j], s);
        }
    }
}

__global__ void k_fin(const float* __restrict__ acc, float* __restrict__ out) {
    if (threadIdx.x == 0 && blockIdx.x == 0) {
        const float nact = fmaxf(acc[1], 1.f);
        const float nfg = fmaxf(acc[2], 1.f);
        out[0] = acc[0] / nact + acc[3] / nfg + acc[4] / nfg;
    }
}

extern "C" void kernel_launch(void* const* d_in, const int* in_sizes, int n_in,
                              void* d_out, int out_size, void* d_ws, size_t ws_size,
                              hipStream_t stream) {
    const float* cls      = (const float*)d_in[0];
    const float* bbox_2d  = (const float*)d_in[1];
    const float* bbox_3d  = (const float*)d_in[2];
    const float* gt_boxes = (const float*)d_in[3];
    const float* gt_3d    = (const float*)d_in[4];
    const int*   gt_labels= (const int*)d_in[5];
    const int*   gt_valid = (const int*)d_in[6];
    const float* anchors  = (const float*)d_in[7];
    const float* means    = (const float*)d_in[8];
    const float* stds     = (const float*)d_in[9];

    float* acc = (float*)d_ws;                                  // 8 floats @ 0
    unsigned long long* colmax = (unsigned long long*)((char*)d_ws + 64); // NB*NG u64
    float* out = (float*)d_out;

    k_init<<<1, BLK, 0, stream>>>(acc, colmax);
    k_colpass<<<NB * NG * COLCH, BLK, 0, stream>>>(gt_boxes, gt_valid, anchors, colmax);
    k_main<<<NB * CHUNKS, BLK, 0, stream>>>(cls, bbox_2d, bbox_3d, gt_boxes, gt_3d,
                                            gt_labels, gt_valid, anchors, means,
                                            stds, colmax, acc);
    k_fin<<<1, 64, 0, stream>>>(acc, out);
}

// Round 3
// 221.108 us; speedup vs baseline: 1.9919x; 1.7941x over previous
//
#include <hip/hip_runtime.h>

#define FEAT_H 32
#define FEAT_W 110
#define STRIDEPX 16
#define NB 8
#define NG 32
#define NANC 36
#define NC 4
#define A_TOTAL (FEAT_H * FEAT_W * NANC) /* 126720 */
#define BLK 256
#define CHUNKS (A_TOTAL / BLK) /* 495, exact */
#define COLCH 16               /* chunks per (b,g) column in colpass */
#define NBLKB 128              /* persistent blocks per batch image in k_main */

__device__ __forceinline__ float smooth_l1(float x) {
    float ax = fabsf(x);
    return ax < 1.f ? 0.5f * ax * ax : ax - 0.5f;
}

// ws layout: acc[8] floats @0, colmax[NB*NG] u64 @64, done counter @64+2048.
// All zeroed by hipMemsetAsync in kernel_launch.

// Column argmax: one block per (b,g,chunk). Packed (iou_bits<<32)|(~a) max
// gives exact first-occurrence argmax (smallest a among ties). IoU >= 0 so
// float bits are monotone as uint. Invalid columns skipped -> colmax stays 0;
// k_main decodes that as ba=0, force=0 (matches reference semantics).
__global__ __launch_bounds__(BLK) void k_colpass(
    const float* __restrict__ gt_boxes, const int* __restrict__ gt_valid,
    const float* __restrict__ anchors, unsigned long long* __restrict__ colmax) {
#pragma clang fp contract(off)
    __shared__ float4 anch4[NANC];
    __shared__ unsigned long long wbest[BLK / 64];
    const int tid = threadIdx.x;
    const int chunk = blockIdx.x % COLCH;
    const int bg = blockIdx.x / COLCH;
    if (!gt_valid[bg]) return; // block-uniform exit, before any barrier
    if (tid < NANC) {
        const float* ap = anchors + tid * 9;
        anch4[tid] = make_float4(ap[0], ap[1], ap[2], ap[3]);
    }
    __syncthreads();
    const float g0 = gt_boxes[bg * 4 + 0], g1 = gt_boxes[bg * 4 + 1];
    const float g2 = gt_boxes[bg * 4 + 2], g3 = gt_boxes[bg * 4 + 3];
    const float ag = (g2 - g0 + 1.f) * (g3 - g1 + 1.f);
    unsigned long long best = 0ull;
    // incremental t/cell: stride COLCH*BLK = 4096 = 113*36 + 28
    int a = chunk * BLK + tid;
    int t = a % NANC;
    int cell = a / NANC;
    for (; a < A_TOTAL; a += COLCH * BLK) {
        const float sx = (float)((cell % FEAT_W) * STRIDEPX);
        const float sy = (float)((cell / FEAT_W) * STRIDEPX);
        const float4 av = anch4[t];
        const float r0 = sx + av.x, r1 = sy + av.y;
        const float r2 = sx + av.z, r3 = sy + av.w;
        const float xx1 = fmaxf(r0, g0), yy1 = fmaxf(r1, g1);
        const float xx2 = fminf(r2, g2), yy2 = fminf(r3, g3);
        const float iw = fmaxf(xx2 - xx1 + 1.f, 0.f);
        const float ih = fmaxf(yy2 - yy1 + 1.f, 0.f);
        const float inter = iw * ih;
        const float ar = (r2 - r0 + 1.f) * (r3 - r1 + 1.f);
        const float iou = inter * __builtin_amdgcn_rcpf(ar + ag - inter);
        unsigned long long p = ((unsigned long long)__float_as_uint(iou) << 32) |
                               (unsigned long long)(0xFFFFFFFFu - (unsigned)a);
        if (p > best) best = p;
        t += 28; cell += 113;
        if (t >= NANC) { t -= NANC; cell += 1; }
    }
    for (int off = 32; off; off >>= 1) {
        unsigned long long o = __shfl_down(best, off, 64);
        if (o > best) best = o;
    }
    if ((tid & 63) == 0) wbest[tid >> 6] = best;
    __syncthreads();
    if (tid == 0) {
        for (int w = 1; w < BLK / 64; ++w)
            if (wbest[w] > best) best = wbest[w];
        atomicMax(&colmax[bg], best);
    }
}

// Persistent: NBLKB blocks per batch image, each grid-striding over chunks.
// acc: [0]=sum_ce, [1]=n_act, [2]=n_fg, [3]=sum_2d, [4]=sum_3d.
__global__ __launch_bounds__(BLK) void k_main(
    const float* __restrict__ cls, const float* __restrict__ bbox_2d,
    const float* __restrict__ bbox_3d, const float* __restrict__ gt_boxes,
    const float* __restrict__ gt_3d, const int* __restrict__ gt_labels,
    const int* __restrict__ gt_valid, const float* __restrict__ anchors,
    const float* __restrict__ means, const float* __restrict__ stds,
    const unsigned long long* __restrict__ colmax, float* __restrict__ acc,
    unsigned* __restrict__ done, float* __restrict__ out) {
#pragma clang fp contract(off)
    __shared__ float anch[NANC * 9];
    __shared__ float4 gtb4_s[NG];
    __shared__ float ags_s[NG];
    __shared__ float gt3_s[NG * 7];
    __shared__ int lbl_s[NG];
    __shared__ int fix_s[NG]; // ba | (force<<31)
    __shared__ float mean_s[11], std_s[11];
    __shared__ unsigned vmask_s;
    __shared__ float red[5][BLK / 64];
    const int tid = threadIdx.x;
    const int b = blockIdx.x / NBLKB;
    const int c0 = blockIdx.x % NBLKB;
    for (int i = tid; i < NANC * 9; i += BLK) anch[i] = anchors[i];
    for (int i = tid; i < NG * 7; i += BLK) gt3_s[i] = gt_3d[b * NG * 7 + i];
    int myval = 0;
    if (tid < NG) {
        const float4 q = ((const float4*)gt_boxes)[b * NG + tid];
        gtb4_s[tid] = q;
        ags_s[tid] = (q.z - q.x + 1.f) * (q.w - q.y + 1.f);
        lbl_s[tid] = gt_labels[b * NG + tid];
        myval = gt_valid[b * NG + tid];
        const unsigned long long p = colmax[b * NG + tid];
        const float gbest = __uint_as_float((unsigned)(p >> 32));
        const int ba = myval ? (int)(0xFFFFFFFFu - (unsigned)(p & 0xFFFFFFFFull)) : 0;
        const int force = (myval && gbest >= 0.35f) ? 1 : 0;
        fix_s[tid] = ba | (force << 31);
    }
    unsigned long long bal = __ballot(tid < NG && myval);
    if (tid == 0) vmask_s = (unsigned)bal;
    if (tid < 11) { mean_s[tid] = means[tid]; std_s[tid] = stds[tid]; }
    __syncthreads();
    const unsigned vmask = vmask_s;

    float sum_ce = 0.f, sum_act = 0.f, sum_fg = 0.f, sum_2d = 0.f, sum_3d = 0.f;

    int chunk = c0;
    const size_t bbase = (size_t)b * A_TOTAL;
    float4 cv = *(const float4*)(cls + (bbase + (size_t)chunk * BLK + tid) * NC);
    while (chunk < CHUNKS) {
        const int nxt = chunk + NBLKB;
        float4 cv_next = make_float4(0.f, 0.f, 0.f, 0.f);
        if (nxt < CHUNKS)
            cv_next = *(const float4*)(cls + (bbase + (size_t)nxt * BLK + tid) * NC);

        const int a = chunk * BLK + tid;
        const int t = a % NANC;
        const int cell = a / NANC;
        const float sx = (float)((cell % FEAT_W) * STRIDEPX);
        const float sy = (float)((cell / FEAT_W) * STRIDEPX);
        const float r0 = sx + anch[t * 9 + 0], r1 = sy + anch[t * 9 + 1];
        const float r2 = sx + anch[t * 9 + 2], r3 = sy + anch[t * 9 + 3];
        const float ar = (r2 - r0 + 1.f) * (r3 - r1 + 1.f);

        float best = -1.0f;
        int agt = 0;
#pragma unroll
        for (int g = 0; g < NG; ++g) {
            const float4 q = gtb4_s[g];
            const float xx1 = fmaxf(r0, q.x), yy1 = fmaxf(r1, q.y);
            const float xx2 = fminf(r2, q.z), yy2 = fminf(r3, q.w);
            const float iw = fmaxf(xx2 - xx1 + 1.f, 0.f);
            const float ih = fmaxf(yy2 - yy1 + 1.f, 0.f);
            const float inter = iw * ih;
            float iou = inter * __builtin_amdgcn_rcpf(ar + ags_s[g] - inter);
            iou = ((vmask >> g) & 1u) ? iou : -1.0f;
            if (iou > best) { best = iou; agt = g; }
        }
        bool fg = best >= 0.5f;
        const int agt_orig = agt;
        // fg.at[ba].max(force); agt.at[ba].set(where(force, g, agt_orig[ba]))
        // gather-before-scatter + last-update-wins, duplicates included.
#pragma unroll
        for (int g = 0; g < NG; ++g) {
            const int f = fix_s[g];
            if (a == (f & 0x7FFFFFFF)) {
                if (f < 0) { agt = g; fg = true; }
                else       { agt = agt_orig; }
            }
        }
        const bool bg = (!fg) && (best < 0.5f) && (best >= 0.0f);
        const float active = (fg || bg) ? 1.f : 0.f;
        const int lbl = fg ? lbl_s[agt] : 0;

        const float c0v = cv.x, c1v = cv.y, c2v = cv.z, c3v = cv.w;
        const float m = fmaxf(fmaxf(c0v, c1v), fmaxf(c2v, c3v));
        const float lse = m + logf(expf(c0v - m) + expf(c1v - m) +
                                   expf(c2v - m) + expf(c3v - m));
        const float csel = (lbl == 0) ? c0v : (lbl == 1) ? c1v : (lbl == 2) ? c2v : c3v;
        sum_ce += (lse - csel) * active;
        sum_act += active;

        if (fg) {
            sum_fg += 1.f;
            const float w = r2 - r0 + 1.f, h = r3 - r1 + 1.f;
            const float cx = r0 + 0.5f * w, cy = r1 + 0.5f * h;
            const float4 G = gtb4_s[agt];
            const float gw = G.z - G.x + 1.f, gh = G.w - G.y + 1.f;
            const float gcx = G.x + 0.5f * gw, gcy = G.y + 0.5f * gh;
            float t2[4];
            t2[0] = (gcx - cx) / w;
            t2[1] = (gcy - cy) / h;
            t2[2] = logf(gw / w);
            t2[3] = logf(gh / h);
            const float4 b2 = *(const float4*)(bbox_2d + (bbase + a) * 4);
            const float b2v[4] = {b2.x, b2.y, b2.z, b2.w};
            float l2 = 0.f;
            for (int k = 0; k < 4; ++k) {
                const float tv = (t2[k] - mean_s[k]) / std_s[k];
                l2 += smooth_l1(b2v[k] - tv);
            }
            sum_2d += l2;
            const float* q3p = &gt3_s[agt * 7];
            const float s4 = anch[t * 9 + 4], s5 = anch[t * 9 + 5];
            const float s6 = anch[t * 9 + 6], s7 = anch[t * 9 + 7], s8 = anch[t * 9 + 8];
            float t3[7];
            t3[0] = (q3p[0] - cx) / w;
            t3[1] = (q3p[1] - cy) / h;
            t3[2] = q3p[2] - s4;
            t3[3] = logf(q3p[3] / s5);
            t3[4] = logf(q3p[4] / s6);
            t3[5] = logf(q3p[5] / s7);
            t3[6] = q3p[6] - s8;
            const float* b3 = bbox_3d + (bbase + a) * 7;
            float l3 = 0.f;
            for (int k = 0; k < 7; ++k) {
                const float tv = (t3[k] - mean_s[4 + k]) / std_s[4 + k];
                l3 += smooth_l1(b3[k] - tv);
            }
            sum_3d += l3;
        }
        cv = cv_next;
        chunk = nxt;
    }

    // block reduce 5 partials -> one atomicAdd set per block
    float vals[5] = {sum_ce, sum_act, sum_fg, sum_2d, sum_3d};
#pragma unroll
    for (int j = 0; j < 5; ++j) {
        float v = vals[j];
        for (int off = 32; off; off >>= 1) v += __shfl_down(v, off, 64);
        if ((tid & 63) == 0) red[j][tid >> 6] = v;
    }
    __syncthreads();
    if (tid == 0) {
        for (int j = 0; j < 5; ++j) {
            float s = 0.f;
            for (int w = 0; w < BLK / 64; ++w) s += red[j][w];
            atomicAdd(&acc[j], s);
        }
        __threadfence();
        const unsigned old = atomicAdd(done, 1u);
        if (old == NB * NBLKB - 1) {
            // last block: all other blocks' acc adds are ordered before their
            // done increment (threadfence) -> visible to device-scope RMWs.
            const float a0 = atomicAdd(&acc[0], 0.f);
            const float a1 = atomicAdd(&acc[1], 0.f);
            const float a2 = atomicAdd(&acc[2], 0.f);
            const float a3 = atomicAdd(&acc[3], 0.f);
            const float a4 = atomicAdd(&acc[4], 0.f);
            const float nact = fmaxf(a1, 1.f);
            const float nfg = fmaxf(a2, 1.f);
            out[0] = a0 / nact + a3 / nfg + a4 / nfg;
        }
    }
}

extern "C" void kernel_launch(void* const* d_in, const int* in_sizes, int n_in,
                              void* d_out, int out_size, void* d_ws, size_t ws_size,
                              hipStream_t stream) {
    const float* cls      = (const float*)d_in[0];
    const float* bbox_2d  = (const float*)d_in[1];
    const float* bbox_3d  = (const float*)d_in[2];
    const float* gt_boxes = (const float*)d_in[3];
    const float* gt_3d    = (const float*)d_in[4];
    const int*   gt_labels= (const int*)d_in[5];
    const int*   gt_valid = (const int*)d_in[6];
    const float* anchors  = (const float*)d_in[7];
    const float* means    = (const float*)d_in[8];
    const float* stds     = (const float*)d_in[9];

    float* acc = (float*)d_ws;                                            // 8 f @0
    unsigned long long* colmax = (unsigned long long*)((char*)d_ws + 64); // 256 u64
    unsigned* done = (unsigned*)((char*)d_ws + 64 + NB * NG * 8);
    float* out = (float*)d_out;

    hipMemsetAsync(d_ws, 0, 4096, stream);
    k_colpass<<<NB * NG * COLCH, BLK, 0, stream>>>(gt_boxes, gt_valid, anchors, colmax);
    k_main<<<NB * NBLKB, BLK, 0, stream>>>(cls, bbox_2d, bbox_3d, gt_boxes, gt_3d,
                                           gt_labels, gt_valid, anchors, means,
                                           stds, colmax, acc, done, out);
}